// Round 3
// baseline (161.410 us; speedup 1.0000x reference)
//
#include <hip/hip_runtime.h>

#define NP 8192
#define KMAX 32
#define LK 0.01f
#define EPSBN 1e-5f

static constexpr int O_OUT = NP * 64;          // 524288
static constexpr int O_POS = O_OUT + NP * 3;   // 548864
static constexpr int O_BAT = O_POS + NP;       // 557056
static constexpr int O_RFL = O_BAT + NP;       // 565248
static constexpr int O_TOT = O_RFL + 4;        // 565252

// ws layout (bytes):
//   0    ecnt (int)
//   4    flag is64 (int)
//   16   bstart[5] (int)
//   64   sums[8][64]  (2048 B)
//   2560 sumsq[8][64] (2048 B)
//   8192 vmaxg (2 MB)
//   8192+2MB vming (2 MB)
#define WS_ECNT   0
#define WS_FLAG   4
#define WS_BST    16
#define WS_SUMS   64
#define WS_SUMSQ  2560
#define WS_VMAX   8192
#define WS_VMIN   (8192 + 2097152)

// ---------------- K0: micro setup — zero stats, int64 detect, segment bsearch
__global__ __launch_bounds__(256) void k0_setup(const int* __restrict__ braw,
                                                int* __restrict__ wsi) {
    __shared__ int flag_s;
    int t = threadIdx.x;
    if (t == 0) flag_s = 0;
    // zero ecnt/flag/bstart/sums/sumsq region: bytes [0, 4608) = 1152 ints
    for (int i = t; i < 1152; i += 256) wsi[i] = 0;
    __syncthreads();
    // int64 little-endian viewed as int32 = [v0,0,v1,0,...] -> breaks sorted/range
    int bad = 0;
    const int4* b4 = (const int4*)braw;
    for (int k = t; k < NP / 4; k += 256) {
        int4 v = b4[k];
        if (v.x < 0 || v.x > 3 || v.y < 0 || v.y > 3 ||
            v.z < 0 || v.z > 3 || v.w < 0 || v.w > 3) bad = 1;
        if (v.x > v.y || v.y > v.z || v.z > v.w) bad = 1;
        if (k > 0 && braw[4 * k - 1] > v.x) bad = 1;
    }
    if (bad) flag_s = 1;
    __syncthreads();
    const int is64 = flag_s;
    if (t == 0) wsi[WS_FLAG / 4] = is64;
    int* bst = wsi + WS_BST / 4;
    if (t < 3) {  // lower_bound for batch value >= b, b=1..3
        int b = t + 1;
        int lo = 0, hi = NP;
        while (lo < hi) {
            int mid = (lo + hi) >> 1;
            int v = is64 ? braw[2 * mid] : braw[mid];
            if (v < b) lo = mid + 1; else hi = mid;
        }
        bst[b] = lo;
    }
    if (t == 3) bst[0] = 0;
    if (t == 4) bst[4] = NP;
}

// ---------------- K12: fused radius search + per-edge MLP, 1 group/block
__global__ __launch_bounds__(256, 4) void k12_fused(const float* __restrict__ xin,
                                                    const float* __restrict__ pos,
                                                    const float* __restrict__ rfl,
                                                    const float* __restrict__ sf,
                                                    const float* __restrict__ w1,
                                                    const float* __restrict__ b1,
                                                    const float* __restrict__ w2,
                                                    const float* __restrict__ b2,
                                                    int* __restrict__ wsi,
                                                    float* __restrict__ vmaxg,
                                                    float* __restrict__ vming) {
    __shared__ int cidx[4][256];      // phase1; reused as cmbmax (4KB)
    __shared__ float cd2[4][256];     // phase1; reused as cmbmin (4KB)
    __shared__ float4 h1b[4][16];     // per-wave h1 exchange
    __shared__ float red[256];
    __shared__ int lcnt[4];
    __shared__ int bst_s[5];
    __shared__ float4 qp4[4];         // (pix, piy, piz, 1/sf[b]) per query
    __shared__ int eflat[4 * KMAX];   // packed (q<<14)|j
    constexpr float R2C = (float)((0.02 * 2.1) * (0.02 * 2.1));

    int t = threadIdx.x;
    int lane = t & 63;
    int w = t >> 6;
    int i0 = blockIdx.x * 4;
    int* bstart = wsi + WS_BST / 4;
    float* sums = (float*)((char*)wsi + WS_SUMS);
    float* sumsq = (float*)((char*)wsi + WS_SUMSQ);
    int* ecnt = wsi + WS_ECNT / 4;

    // weights resident in registers; lane = output channel
    float w1c[8];
#pragma unroll
    for (int f = 0; f < 8; f++) w1c[f] = w1[f * 64 + lane];
    float b1c = b1[lane];
    float4 w2c[16];
#pragma unroll
    for (int m = 0; m < 16; m++) {
        w2c[m].x = w2[(4 * m + 0) * 64 + lane];
        w2c[m].y = w2[(4 * m + 1) * 64 + lane];
        w2c[m].z = w2[(4 * m + 2) * 64 + lane];
        w2c[m].w = w2[(4 * m + 3) * 64 + lane];
    }
    float b2c = b2[lane];

    if (t < 5) bst_s[t] = bstart[t];
    if (t < 4) lcnt[t] = 0;
    __syncthreads();
    if (t < 4) {
        int i = i0 + t;
        int b = (i >= bst_s[1]) + (i >= bst_s[2]) + (i >= bst_s[3]);
        qp4[t] = make_float4(pos[3 * i], pos[3 * i + 1], pos[3 * i + 2], 1.0f / sf[b]);
    }
    __syncthreads();

    // ---- phase 1: scan the 4 queries' batch segments
    float qx[4], qy[4], qz[4], qs[4];
    int ql[4], qh[4];
    int lo = NP, hi = 0;
#pragma unroll
    for (int q = 0; q < 4; q++) {
        float4 p = qp4[q];
        qx[q] = p.x; qy[q] = p.y; qz[q] = p.z;
        qs[q] = p.x * p.x + p.y * p.y + p.z * p.z;
        int i = i0 + q;
        int b = (i >= bst_s[1]) + (i >= bst_s[2]) + (i >= bst_s[3]);
        ql[q] = bst_s[b]; qh[q] = bst_s[b + 1];
        lo = min(lo, ql[q]); hi = max(hi, qh[q]);
    }
    for (int j = lo + t; j < hi; j += 256) {
        float xj = pos[3 * j], yj = pos[3 * j + 1], zj = pos[3 * j + 2];
        float sj = xj * xj + yj * yj + zj * zj;
#pragma unroll
        for (int q = 0; q < 4; q++) {
            if (j >= ql[q] && j < qh[q]) {
                float d2 = qs[q] + sj - 2.0f * (qx[q] * xj + qy[q] * yj + qz[q] * zj);
                if (d2 < R2C) {
                    int p = atomicAdd(&lcnt[q], 1);
                    if (p < 256) { cidx[q][p] = j; cd2[q][p] = d2; }
                }
            }
        }
    }
    __syncthreads();
    if (t < 4) {  // rare overflow: exact nearest-KMAX selection
        int c = lcnt[t]; c = c > 256 ? 256 : c;
        if (c > KMAX) {
            for (int s = 0; s < KMAX; s++) {
                int bi = s; float bd = cd2[t][s];
                for (int r = s + 1; r < c; r++)
                    if (cd2[t][r] < bd) { bd = cd2[t][r]; bi = r; }
                float tf = cd2[t][s]; cd2[t][s] = cd2[t][bi]; cd2[t][bi] = tf;
                int ti = cidx[t][s]; cidx[t][s] = cidx[t][bi]; cidx[t][bi] = ti;
            }
            c = KMAX;
        }
        lcnt[t] = c;
    }
    __syncthreads();
    int off_q[5];
    off_q[0] = 0;
#pragma unroll
    for (int q = 0; q < 4; q++) off_q[q + 1] = off_q[q] + lcnt[q];
    const int total = off_q[4];
#pragma unroll
    for (int q = 0; q < 4; q++)
        if (t < lcnt[q]) eflat[off_q[q] + t] = (q << 14) | cidx[q][t];
    __syncthreads();

    // ---- phase 2: waves take edges round-robin; lane = channel
    float vmax0 = -3.4e38f, vmax1 = -3.4e38f, vmax2 = -3.4e38f, vmax3 = -3.4e38f;
    float vmin0 = 3.4e38f, vmin1 = 3.4e38f, vmin2 = 3.4e38f, vmin3 = 3.4e38f;
    float ssum = 0.f, ssq = 0.f;
    {
        int e = w;
        float4 xi4; float pjx = 0, pjy = 0, pjz = 0, rj = 0, ri = 0; float4 qv; int q = 0;
        xi4 = make_float4(0, 0, 0, 0); qv = make_float4(0, 0, 0, 0);
        if (e < total) {  // prologue prefetch
            int pk = eflat[e];
            int j = pk & 0x3fff; q = pk >> 14;
            xi4 = ((const float4*)xin)[j];
            pjx = pos[3 * j]; pjy = pos[3 * j + 1]; pjz = pos[3 * j + 2];
            rj = rfl[j];
            qv = qp4[q];
            ri = rfl[i0 + q];
        }
        while (e < total) {
            int en = e + 4;
            float rs = qv.w;
            float f4 = (pjx - qv.x) * rs;
            float f5 = (pjy - qv.y) * rs;
            float f6 = (pjz - qv.z) * rs;
            float f7 = rj - ri;
            float a = b1c + xi4.x * w1c[0] + xi4.y * w1c[1] + xi4.z * w1c[2] + xi4.w * w1c[3]
                          + f4 * w1c[4] + f5 * w1c[5] + f6 * w1c[6] + f7 * w1c[7];
            float h1 = a > 0.f ? a : LK * a;
            int qcur = q;
            ((float*)&h1b[w][0])[lane] = h1;
            // prefetch next edge (global loads stay in flight across the waitcnt)
            float4 xi4n = xi4; float pjxn = pjx, pjyn = pjy, pjzn = pjz, rjn = rj, rin = ri;
            float4 qvn = qv; int qn = q;
            if (en < total) {
                int pkn = eflat[en];
                int jn = pkn & 0x3fff; qn = pkn >> 14;
                xi4n = ((const float4*)xin)[jn];
                pjxn = pos[3 * jn]; pjyn = pos[3 * jn + 1]; pjzn = pos[3 * jn + 2];
                rjn = rfl[jn];
                qvn = qp4[qn];
                rin = rfl[i0 + qn];
            }
            asm volatile("s_waitcnt lgkmcnt(0)" ::: "memory");  // LDS order only
            float acc = b2c;
#pragma unroll
            for (int m = 0; m < 16; m++) {
                float4 hv = h1b[w][m];      // broadcast ds_read_b128
                acc += hv.x * w2c[m].x + hv.y * w2c[m].y + hv.z * w2c[m].z + hv.w * w2c[m].w;
            }
            float h2 = acc > 0.f ? acc : LK * acc;
            if (qcur == 0)      { vmax0 = fmaxf(vmax0, h2); vmin0 = fminf(vmin0, h2); }
            else if (qcur == 1) { vmax1 = fmaxf(vmax1, h2); vmin1 = fminf(vmin1, h2); }
            else if (qcur == 2) { vmax2 = fmaxf(vmax2, h2); vmin2 = fminf(vmin2, h2); }
            else                { vmax3 = fmaxf(vmax3, h2); vmin3 = fminf(vmin3, h2); }
            ssum += h2; ssq += h2 * h2;
            xi4 = xi4n; pjx = pjxn; pjy = pjyn; pjz = pjzn; rj = rjn; ri = rin;
            qv = qvn; q = qn; e = en;
        }
    }
    // ---- cross-wave max/min combine (reuse cidx/cd2 as [srcwave][q][64])
    float* cmbmax = (float*)cidx;
    float* cmbmin = (float*)cd2;
    __syncthreads();
    cmbmax[((w << 2) | 0) * 64 + lane] = vmax0;
    cmbmax[((w << 2) | 1) * 64 + lane] = vmax1;
    cmbmax[((w << 2) | 2) * 64 + lane] = vmax2;
    cmbmax[((w << 2) | 3) * 64 + lane] = vmax3;
    cmbmin[((w << 2) | 0) * 64 + lane] = vmin0;
    cmbmin[((w << 2) | 1) * 64 + lane] = vmin1;
    cmbmin[((w << 2) | 2) * 64 + lane] = vmin2;
    cmbmin[((w << 2) | 3) * 64 + lane] = vmin3;
    __syncthreads();
    {
        float mx = fmaxf(fmaxf(cmbmax[((0 << 2) | w) * 64 + lane], cmbmax[((1 << 2) | w) * 64 + lane]),
                         fmaxf(cmbmax[((2 << 2) | w) * 64 + lane], cmbmax[((3 << 2) | w) * 64 + lane]));
        float mn = fminf(fminf(cmbmin[((0 << 2) | w) * 64 + lane], cmbmin[((1 << 2) | w) * 64 + lane]),
                         fminf(cmbmin[((2 << 2) | w) * 64 + lane], cmbmin[((3 << 2) | w) * 64 + lane]));
        vmaxg[(i0 + w) * 64 + lane] = mx;   // every query has its self-edge
        vming[(i0 + w) * 64 + lane] = mn;
    }
    // ---- BN stats: block-reduce then 8-way banked atomics
    red[t] = ssum;
    __syncthreads();
    if (t < 64) atomicAdd(&sums[((blockIdx.x & 7) << 6) + t],
                          red[t] + red[t + 64] + red[t + 128] + red[t + 192]);
    __syncthreads();
    red[t] = ssq;
    __syncthreads();
    if (t < 64) atomicAdd(&sumsq[((blockIdx.x & 7) << 6) + t],
                          red[t] + red[t + 64] + red[t + 128] + red[t + 192]);
    if (t == 0) atomicAdd(ecnt, total);
}

// ---------------- K3: BN affine + max/min pick + tuple passthrough
__global__ __launch_bounds__(256) void k3_fin(const int* __restrict__ wsi,
                                              const float* __restrict__ vmaxg,
                                              const float* __restrict__ vming,
                                              const float* __restrict__ gamma,
                                              const float* __restrict__ beta,
                                              const float* __restrict__ pos,
                                              const int* __restrict__ braw,
                                              const float* __restrict__ rfl,
                                              const float* __restrict__ sf,
                                              float* __restrict__ out) {
    int t = blockIdx.x * 256 + threadIdx.x;
    const float* sums = (const float*)((const char*)wsi + WS_SUMS);
    const float* sumsq = (const float*)((const char*)wsi + WS_SUMSQ);
    if (t < O_OUT) {
        int c = t & 63;
        float s = 0.f, s2 = 0.f;
#pragma unroll
        for (int b = 0; b < 8; b++) { s += sums[b * 64 + c]; s2 += sumsq[b * 64 + c]; }
        float cntf = (float)wsi[WS_ECNT / 4];
        float mean = s / cntf;
        float var = s2 / cntf - mean * mean;
        var = var > 0.f ? var : 0.f;
        float inv = 1.0f / sqrtf(var + EPSBN);
        float scl = gamma[c] * inv;
        float shf = beta[c] - mean * scl;
        float v = (scl >= 0.f) ? vmaxg[t] : vming[t];
        out[t] = scl * v + shf;
    } else if (t < O_POS) {
        out[t] = pos[t - O_OUT];
    } else if (t < O_BAT) {
        int i = t - O_POS;
        int is64 = wsi[WS_FLAG / 4];
        out[t] = (float)(is64 ? braw[2 * i] : braw[i]);
    } else if (t < O_RFL) {
        out[t] = rfl[t - O_BAT];
    } else if (t < O_TOT) {
        out[t] = sf[t - O_RFL];
    }
}

extern "C" void kernel_launch(void* const* d_in, const int* in_sizes, int n_in,
                              void* d_out, int out_size, void* d_ws, size_t ws_size,
                              hipStream_t stream) {
    const float* xin  = (const float*)d_in[0];
    const float* pos  = (const float*)d_in[1];
    const float* rfl  = (const float*)d_in[2];
    const float* sf   = (const float*)d_in[3];
    const float* w1   = (const float*)d_in[4];
    const float* b1   = (const float*)d_in[5];
    const float* w2   = (const float*)d_in[6];
    const float* b2   = (const float*)d_in[7];
    const float* gam  = (const float*)d_in[8];
    const float* bet  = (const float*)d_in[9];
    const int*   brw  = (const int*)d_in[10];
    float* out = (float*)d_out;

    int*   wsi   = (int*)d_ws;
    float* vmaxg = (float*)((char*)d_ws + WS_VMAX);
    float* vming = (float*)((char*)d_ws + WS_VMIN);

    k0_setup<<<1, 256, 0, stream>>>(brw, wsi);
    k12_fused<<<NP / 4, 256, 0, stream>>>(xin, pos, rfl, sf, w1, b1, w2, b2,
                                          wsi, vmaxg, vming);
    k3_fin<<<(O_TOT + 255) / 256, 256, 0, stream>>>(wsi, vmaxg, vming, gam, bet,
                                                    pos, brw, rfl, sf, out);
}

// Round 5
// 131.861 us; speedup vs baseline: 1.2241x; 1.2241x over previous
//
#include <hip/hip_runtime.h>

typedef _Float16 half2v __attribute__((ext_vector_type(2)));

#define NP 8192
#define KMAX 32
#define CCAP 64            // candidate cap per query (E[c]~10; P(>64) ~ 0)
#define CHUNK 1024         // points staged in LDS per chunk
#define LK 0.01f
#define EPSBN 1e-5f
#define NBANK 16

static constexpr int O_OUT = NP * 64;          // 524288
static constexpr int O_POS = O_OUT + NP * 3;   // 548864
static constexpr int O_BAT = O_POS + NP;       // 557056
static constexpr int O_RFL = O_BAT + NP;       // 565248
static constexpr int O_TOT = O_RFL + 4;        // 565252

// ws float offsets
#define F_ECNT  0                       // 1 int
#define F_SUMS  16                      // 16 x 64
#define F_SUMSQ (16 + 1024)             // 16 x 64
#define F_VMAX  4096                    // NP*64
#define F_VMIN  (4096 + 524288)

__device__ __forceinline__ float dot2f(half2v a, half2v b, float c) {
#if __has_builtin(__builtin_amdgcn_fdot2)
    return __builtin_amdgcn_fdot2(a, b, c, false);
#else
    return c + (float)a[0] * (float)b[0] + (float)a[1] * (float)b[1];
#endif
}

// ---------------- K1: fused radius search (LDS-staged) + per-edge MLP
// Block = 4 waves, 4 queries; wave-per-edge round-robin; lane = channel.
__global__ __launch_bounds__(256, 3) void k1_fused(const float* __restrict__ xin,
                                                   const float* __restrict__ pos,
                                                   const float* __restrict__ rfl,
                                                   const float* __restrict__ sf,
                                                   const float* __restrict__ w1,
                                                   const float* __restrict__ b1,
                                                   const float* __restrict__ w2,
                                                   const float* __restrict__ b2,
                                                   const int* __restrict__ braw,
                                                   float* __restrict__ wsf) {
    __shared__ float spos[CHUNK * 3];          // 12 KB; reused for cross-wave combine
    __shared__ int cidx[4][CCAP];
    __shared__ float cd2[4][CCAP];
    __shared__ __align__(16) _Float16 h1h[4][64];
    __shared__ float red[256];
    __shared__ int lcnt[4];
    __shared__ int bst_s[5];
    __shared__ float4 qp4[4];                  // (pix,piy,piz, 1/sf[b])
    __shared__ int eflat[4 * KMAX];            // packed (q<<14)|j
    constexpr float R2C = (float)((0.02 * 2.1) * (0.02 * 2.1));

    int t = threadIdx.x;
    int lane = t & 63;
    int w = t >> 6;
    int i0 = blockIdx.x * 4;

    int* ecnt = (int*)wsf;
    float* sums = wsf + F_SUMS;
    float* sumsq = wsf + F_SUMSQ;
    float* vmaxg = wsf + F_VMAX;
    float* vming = wsf + F_VMIN;

    // int64 LE viewed as int32 => index NP-1 is a hi-word (0); int32 sorted => 3.
    const int is64 = (braw[NP - 1] == 0) ? 1 : 0;
    if (t == 0) { bst_s[0] = 0; bst_s[4] = NP; }
    if (t < 3) {               // lower_bound(batch >= b), b = 1..3
        int b = t + 1, lo = 0, hi = NP;
        while (lo < hi) {
            int mid = (lo + hi) >> 1;
            int v = is64 ? braw[2 * mid] : braw[mid];
            if (v < b) lo = mid + 1; else hi = mid;
        }
        bst_s[b] = lo;
    }
    if (t < 4) lcnt[t] = 0;

    // ---- weights resident in registers; lane = output channel
    float w1c[8];
#pragma unroll
    for (int f = 0; f < 8; f++) w1c[f] = w1[f * 64 + lane];
    float b1c = b1[lane];
    half2v w2c[32];
#pragma unroll
    for (int m = 0; m < 32; m++) {
        half2v v;
        v[0] = (_Float16)w2[(2 * m + 0) * 64 + lane];
        v[1] = (_Float16)w2[(2 * m + 1) * 64 + lane];
        w2c[m] = v;
    }
    float b2c = b2[lane];
    __syncthreads();

    if (t < 4) {
        int i = i0 + t;
        int b = (i >= bst_s[1]) + (i >= bst_s[2]) + (i >= bst_s[3]);
        qp4[t] = make_float4(pos[3 * i], pos[3 * i + 1], pos[3 * i + 2], 1.0f / sf[b]);
    }
    __syncthreads();

    // ---- phase 1: chunked LDS-staged segment scan
    float qx[4], qy[4], qz[4], qs[4];
    int ql[4], qh[4];
    int lo = NP, hi = 0;
#pragma unroll
    for (int q = 0; q < 4; q++) {
        float4 p = qp4[q];
        qx[q] = p.x; qy[q] = p.y; qz[q] = p.z;
        qs[q] = p.x * p.x + p.y * p.y + p.z * p.z;
        int i = i0 + q;
        int b = (i >= bst_s[1]) + (i >= bst_s[2]) + (i >= bst_s[3]);
        ql[q] = bst_s[b]; qh[q] = bst_s[b + 1];
        lo = min(lo, ql[q]); hi = max(hi, qh[q]);
    }
    for (int base = lo; base < hi; base += CHUNK) {
        int csz = min(CHUNK, hi - base);
        int nf = csz * 3;
        __syncthreads();
        for (int k = t; k < nf; k += 256) spos[k] = pos[3 * base + k];
        __syncthreads();
        for (int k = t; k < csz; k += 256) {
            float xj = spos[3 * k], yj = spos[3 * k + 1], zj = spos[3 * k + 2];
            float sj = xj * xj + yj * yj + zj * zj;
            int j = base + k;
#pragma unroll
            for (int q = 0; q < 4; q++) {
                if (j >= ql[q] && j < qh[q]) {
                    float d2 = qs[q] + sj - 2.0f * (qx[q] * xj + qy[q] * yj + qz[q] * zj);
                    if (d2 < R2C) {
                        int p = atomicAdd(&lcnt[q], 1);
                        if (p < CCAP) { cidx[q][p] = j; cd2[q][p] = d2; }
                    }
                }
            }
        }
    }
    __syncthreads();
    if (t < 4) {               // rare overflow: exact nearest-KMAX selection
        int c = lcnt[t]; c = c > CCAP ? CCAP : c;
        if (c > KMAX) {
            for (int s = 0; s < KMAX; s++) {
                int bi = s; float bd = cd2[t][s];
                for (int r = s + 1; r < c; r++)
                    if (cd2[t][r] < bd) { bd = cd2[t][r]; bi = r; }
                float tf = cd2[t][s]; cd2[t][s] = cd2[t][bi]; cd2[t][bi] = tf;
                int ti = cidx[t][s]; cidx[t][s] = cidx[t][bi]; cidx[t][bi] = ti;
            }
            c = KMAX;
        }
        lcnt[t] = c;
    }
    __syncthreads();
    int off_q[5];
    off_q[0] = 0;
#pragma unroll
    for (int q = 0; q < 4; q++) off_q[q + 1] = off_q[q] + lcnt[q];
    const int total = off_q[4];
#pragma unroll
    for (int q = 0; q < 4; q++)
        if (t < lcnt[q]) eflat[off_q[q] + t] = (q << 14) | cidx[q][t];
    __syncthreads();

    // ---- phase 2: waves take edges round-robin; lane = channel
    float vmax0 = -3.4e38f, vmax1 = -3.4e38f, vmax2 = -3.4e38f, vmax3 = -3.4e38f;
    float vmin0 = 3.4e38f, vmin1 = 3.4e38f, vmin2 = 3.4e38f, vmin3 = 3.4e38f;
    float ssum = 0.f, ssq = 0.f;
    {
        int e = w;
        float4 xi4 = make_float4(0, 0, 0, 0);
        float pjx = 0, pjy = 0, pjz = 0, rj = 0, ri = 0;
        float4 qv = make_float4(0, 0, 0, 1); int q = 0;
        if (e < total) {       // prologue prefetch
            int pk = eflat[e];
            int j = pk & 0x3fff; q = pk >> 14;
            xi4 = ((const float4*)xin)[j];
            pjx = pos[3 * j]; pjy = pos[3 * j + 1]; pjz = pos[3 * j + 2];
            rj = rfl[j];
            qv = qp4[q];
            ri = rfl[i0 + q];
        }
        while (e < total) {
            int en = e + 4;
            float rs = qv.w;
            float f4 = (pjx - qv.x) * rs;
            float f5 = (pjy - qv.y) * rs;
            float f6 = (pjz - qv.z) * rs;
            float f7 = rj - ri;
            float a = b1c + xi4.x * w1c[0] + xi4.y * w1c[1] + xi4.z * w1c[2] + xi4.w * w1c[3]
                          + f4 * w1c[4] + f5 * w1c[5] + f6 * w1c[6] + f7 * w1c[7];
            float h1 = a > 0.f ? a : LK * a;
            int qcur = q;
            h1h[w][lane] = (_Float16)h1;       // ds_write_b16
            // prefetch next edge (global loads stay in flight across lgkm wait)
            float4 xi4n = xi4; float pjxn = pjx, pjyn = pjy, pjzn = pjz, rjn = rj, rin = ri;
            float4 qvn = qv; int qn = q;
            if (en < total) {
                int pkn = eflat[en];
                int jn = pkn & 0x3fff; qn = pkn >> 14;
                xi4n = ((const float4*)xin)[jn];
                pjxn = pos[3 * jn]; pjyn = pos[3 * jn + 1]; pjzn = pos[3 * jn + 2];
                rjn = rfl[jn];
                qvn = qp4[qn];
                rin = rfl[i0 + qn];
            }
            asm volatile("s_waitcnt lgkmcnt(0)" ::: "memory");
            float acc = b2c;
            const float4* hp = (const float4*)&h1h[w][0];
#pragma unroll
            for (int k = 0; k < 8; k++) {
                float4 rv = hp[k];             // broadcast ds_read_b128 = 8 halves
                half2v* h2p = (half2v*)&rv;
                acc = dot2f(h2p[0], w2c[4 * k + 0], acc);
                acc = dot2f(h2p[1], w2c[4 * k + 1], acc);
                acc = dot2f(h2p[2], w2c[4 * k + 2], acc);
                acc = dot2f(h2p[3], w2c[4 * k + 3], acc);
            }
            float h2 = acc > 0.f ? acc : LK * acc;
            if (qcur == 0)      { vmax0 = fmaxf(vmax0, h2); vmin0 = fminf(vmin0, h2); }
            else if (qcur == 1) { vmax1 = fmaxf(vmax1, h2); vmin1 = fminf(vmin1, h2); }
            else if (qcur == 2) { vmax2 = fmaxf(vmax2, h2); vmin2 = fminf(vmin2, h2); }
            else                { vmax3 = fmaxf(vmax3, h2); vmin3 = fminf(vmin3, h2); }
            ssum += h2; ssq += h2 * h2;
            xi4 = xi4n; pjx = pjxn; pjy = pjyn; pjz = pjzn; rj = rjn; ri = rin;
            qv = qvn; q = qn; e = en;
        }
    }
    // ---- cross-wave max/min combine (reuse spos: [srcwave*4+q][64])
    float* cmbmax = spos;
    float* cmbmin = spos + 1024;
    __syncthreads();
    cmbmax[((w << 2) | 0) * 64 + lane] = vmax0;
    cmbmax[((w << 2) | 1) * 64 + lane] = vmax1;
    cmbmax[((w << 2) | 2) * 64 + lane] = vmax2;
    cmbmax[((w << 2) | 3) * 64 + lane] = vmax3;
    cmbmin[((w << 2) | 0) * 64 + lane] = vmin0;
    cmbmin[((w << 2) | 1) * 64 + lane] = vmin1;
    cmbmin[((w << 2) | 2) * 64 + lane] = vmin2;
    cmbmin[((w << 2) | 3) * 64 + lane] = vmin3;
    __syncthreads();
    {
        float mx = fmaxf(fmaxf(cmbmax[((0 << 2) | w) * 64 + lane], cmbmax[((1 << 2) | w) * 64 + lane]),
                         fmaxf(cmbmax[((2 << 2) | w) * 64 + lane], cmbmax[((3 << 2) | w) * 64 + lane]));
        float mn = fminf(fminf(cmbmin[((0 << 2) | w) * 64 + lane], cmbmin[((1 << 2) | w) * 64 + lane]),
                         fminf(cmbmin[((2 << 2) | w) * 64 + lane], cmbmin[((3 << 2) | w) * 64 + lane]));
        vmaxg[(i0 + w) * 64 + lane] = mx;      // every query has its self-edge
        vming[(i0 + w) * 64 + lane] = mn;
    }
    // ---- BN stats: block-reduce then 16-way banked atomics
    red[t] = ssum;
    __syncthreads();
    if (t < 64) atomicAdd(&sums[((blockIdx.x & (NBANK - 1)) << 6) + t],
                          red[t] + red[t + 64] + red[t + 128] + red[t + 192]);
    __syncthreads();
    red[t] = ssq;
    __syncthreads();
    if (t < 64) atomicAdd(&sumsq[((blockIdx.x & (NBANK - 1)) << 6) + t],
                          red[t] + red[t + 64] + red[t + 128] + red[t + 192]);
    if (t == 0) atomicAdd(ecnt, total);
}

// ---------------- K2: BN affine + max/min pick + tuple passthrough
__global__ __launch_bounds__(256) void k2_fin(const float* __restrict__ wsf,
                                              const float* __restrict__ gamma,
                                              const float* __restrict__ beta,
                                              const float* __restrict__ pos,
                                              const int* __restrict__ braw,
                                              const float* __restrict__ rfl,
                                              const float* __restrict__ sf,
                                              float* __restrict__ out) {
    int t = blockIdx.x * 256 + threadIdx.x;
    const float* sums = wsf + F_SUMS;
    const float* sumsq = wsf + F_SUMSQ;
    const float* vmaxg = wsf + F_VMAX;
    const float* vming = wsf + F_VMIN;
    if (t < O_OUT) {
        int c = t & 63;
        float s = 0.f, s2 = 0.f;
#pragma unroll
        for (int b = 0; b < NBANK; b++) { s += sums[b * 64 + c]; s2 += sumsq[b * 64 + c]; }
        float cntf = (float)((const int*)wsf)[F_ECNT];
        float mean = s / cntf;
        float var = s2 / cntf - mean * mean;
        var = var > 0.f ? var : 0.f;
        float inv = 1.0f / sqrtf(var + EPSBN);
        float scl = gamma[c] * inv;
        float shf = beta[c] - mean * scl;
        float v = (scl >= 0.f) ? vmaxg[t] : vming[t];
        out[t] = scl * v + shf;
    } else if (t < O_POS) {
        out[t] = pos[t - O_OUT];
    } else if (t < O_BAT) {
        int i = t - O_POS;
        int is64 = (braw[NP - 1] == 0) ? 1 : 0;
        out[t] = (float)(is64 ? braw[2 * i] : braw[i]);
    } else if (t < O_RFL) {
        out[t] = rfl[t - O_BAT];
    } else if (t < O_TOT) {
        out[t] = sf[t - O_RFL];
    }
}

extern "C" void kernel_launch(void* const* d_in, const int* in_sizes, int n_in,
                              void* d_out, int out_size, void* d_ws, size_t ws_size,
                              hipStream_t stream) {
    const float* xin  = (const float*)d_in[0];
    const float* pos  = (const float*)d_in[1];
    const float* rfl  = (const float*)d_in[2];
    const float* sf   = (const float*)d_in[3];
    const float* w1   = (const float*)d_in[4];
    const float* b1   = (const float*)d_in[5];
    const float* w2   = (const float*)d_in[6];
    const float* b2   = (const float*)d_in[7];
    const float* gam  = (const float*)d_in[8];
    const float* bet  = (const float*)d_in[9];
    const int*   brw  = (const int*)d_in[10];
    float* out = (float*)d_out;
    float* wsf = (float*)d_ws;

    hipMemsetAsync(d_ws, 0, (F_SUMSQ + 1024) * 4, stream);   // ecnt + sums + sumsq

    k1_fused<<<NP / 4, 256, 0, stream>>>(xin, pos, rfl, sf, w1, b1, w2, b2, brw, wsf);
    k2_fin<<<(O_TOT + 255) / 256, 256, 0, stream>>>(wsf, gam, bet, pos, brw, rfl, sf, out);
}

// Round 6
// 123.533 us; speedup vs baseline: 1.3066x; 1.0674x over previous
//
#include <hip/hip_runtime.h>

typedef _Float16 half2v __attribute__((ext_vector_type(2)));

#define NP 8192
#define KMAX 32
#define CCAP 64            // candidate cap per query (E[c]~10; P(>64) ~ 0)
#define CHUNK 1024         // points staged in LDS per chunk
#define LK 0.01f
#define EPSBN 1e-5f
#define NBANK 16

static constexpr int O_OUT = NP * 64;          // 524288
static constexpr int O_POS = O_OUT + NP * 3;   // 548864
static constexpr int O_BAT = O_POS + NP;       // 557056
static constexpr int O_RFL = O_BAT + NP;       // 565248
static constexpr int O_TOT = O_RFL + 4;        // 565252

// ws float offsets
#define F_ECNT  0                       // 1 int
#define F_SUMS  16                      // 16 x 64
#define F_SUMSQ (16 + 1024)             // 16 x 64
#define F_VSEL  4096                    // NP*64 (gamma-sign-selected max/min)

__device__ __forceinline__ float dot2f(half2v a, half2v b, float c) {
#if __has_builtin(__builtin_amdgcn_fdot2)
    return __builtin_amdgcn_fdot2(a, b, c, false);
#else
    return c + (float)a[0] * (float)b[0] + (float)a[1] * (float)b[1];
#endif
}

// ---------------- K1: fused radius search (LDS-staged) + per-edge MLP
// Block = 4 waves, 4 queries. Phase 2 split: 2a all-h1 -> LDS, 2b layer2.
// waves_per_eu(4,4): cap scheduler occupancy target so weights stay in VGPRs.
__global__ __launch_bounds__(256) __attribute__((amdgpu_waves_per_eu(4, 4)))
void k1_fused(const float* __restrict__ xin,
              const float* __restrict__ pos,
              const float* __restrict__ rfl,
              const float* __restrict__ sf,
              const float* __restrict__ w1,
              const float* __restrict__ b1,
              const float* __restrict__ w2,
              const float* __restrict__ b2,
              const float* __restrict__ gamma,
              const int* __restrict__ braw,
              float* __restrict__ wsf) {
    // shbuf: phase1 = spos float4[CHUNK] (16KB); phase2 = h1all[128][64] f16
    // (16KB); epilogue = cmbmax/cmbmin (8KB)
    __shared__ __align__(16) char shbuf[CHUNK * 16];
    __shared__ __align__(16) float feat[128][8];   // per-edge 8-feature vectors
    __shared__ int cidx[4][CCAP];
    __shared__ float cd2[4][CCAP];
    __shared__ float red[256];
    __shared__ int lcnt[4];
    __shared__ int bst_s[5];
    __shared__ float4 qp4[4];                      // (pix,piy,piz, 1/sf[b])
    __shared__ float rfl_i[4];
    __shared__ int eflat[4 * KMAX];                // packed (q<<14)|j
    constexpr float R2C = (float)((0.02 * 2.1) * (0.02 * 2.1));

    int t = threadIdx.x;
    int lane = t & 63;
    int w = t >> 6;
    int i0 = blockIdx.x * 4;

    int* ecnt = (int*)wsf;
    float* sums = wsf + F_SUMS;
    float* sumsq = wsf + F_SUMSQ;
    float* vsel = wsf + F_VSEL;

    // int64 LE viewed as int32 => index NP-1 is a hi-word (0); int32 sorted => 3.
    const int is64 = (braw[NP - 1] == 0) ? 1 : 0;
    if (t == 0) { bst_s[0] = 0; bst_s[4] = NP; }
    if (t < 3) {               // lower_bound(batch >= b), b = 1..3
        int b = t + 1, lo = 0, hi = NP;
        while (lo < hi) {
            int mid = (lo + hi) >> 1;
            int v = is64 ? braw[2 * mid] : braw[mid];
            if (v < b) lo = mid + 1; else hi = mid;
        }
        bst_s[b] = lo;
    }
    if (t < 4) lcnt[t] = 0;

    // ---- weights resident in registers; lane = output channel
    float w1c[8];
#pragma unroll
    for (int f = 0; f < 8; f++) w1c[f] = w1[f * 64 + lane];
    float b1c = b1[lane];
    half2v w2c[32];
#pragma unroll
    for (int m = 0; m < 32; m++) {
        half2v v;
        v[0] = (_Float16)w2[(2 * m + 0) * 64 + lane];
        v[1] = (_Float16)w2[(2 * m + 1) * 64 + lane];
        w2c[m] = v;
    }
    float b2c = b2[lane];
    float gamc = gamma[lane];
    __syncthreads();

    if (t < 4) {
        int i = i0 + t;
        int b = (i >= bst_s[1]) + (i >= bst_s[2]) + (i >= bst_s[3]);
        qp4[t] = make_float4(pos[3 * i], pos[3 * i + 1], pos[3 * i + 2], 1.0f / sf[b]);
        rfl_i[t] = rfl[i];
    }
    __syncthreads();

    // ---- phase 1: chunked LDS-staged segment scan (float4 = xyz + |p|^2)
    float qx[4], qy[4], qz[4], qs[4];
    int ql[4], qh[4];
    int lo = NP, hi = 0;
#pragma unroll
    for (int q = 0; q < 4; q++) {
        float4 p = qp4[q];
        qx[q] = p.x; qy[q] = p.y; qz[q] = p.z;
        qs[q] = p.x * p.x + p.y * p.y + p.z * p.z;
        int i = i0 + q;
        int b = (i >= bst_s[1]) + (i >= bst_s[2]) + (i >= bst_s[3]);
        ql[q] = bst_s[b]; qh[q] = bst_s[b + 1];
        lo = min(lo, ql[q]); hi = max(hi, qh[q]);
    }
    float4* spos = (float4*)shbuf;
    for (int base = lo; base < hi; base += CHUNK) {
        int csz = min(CHUNK, hi - base);
        __syncthreads();
        for (int k = t; k < csz; k += 256) {
            int j = base + k;
            float xj = pos[3 * j], yj = pos[3 * j + 1], zj = pos[3 * j + 2];
            spos[k] = make_float4(xj, yj, zj, xj * xj + yj * yj + zj * zj);
        }
        __syncthreads();
        for (int k = t; k < csz; k += 256) {
            float4 pj = spos[k];          // one ds_read_b128 per candidate
            int j = base + k;
#pragma unroll
            for (int q = 0; q < 4; q++) {
                if (j >= ql[q] && j < qh[q]) {
                    float d2 = qs[q] + pj.w - 2.0f * (qx[q] * pj.x + qy[q] * pj.y + qz[q] * pj.z);
                    if (d2 < R2C) {
                        int p = atomicAdd(&lcnt[q], 1);
                        if (p < CCAP) { cidx[q][p] = j; cd2[q][p] = d2; }
                    }
                }
            }
        }
    }
    __syncthreads();
    if (t < 4) {               // rare overflow: exact nearest-KMAX selection
        int c = lcnt[t]; c = c > CCAP ? CCAP : c;
        if (c > KMAX) {
            for (int s = 0; s < KMAX; s++) {
                int bi = s; float bd = cd2[t][s];
                for (int r = s + 1; r < c; r++)
                    if (cd2[t][r] < bd) { bd = cd2[t][r]; bi = r; }
                float tf = cd2[t][s]; cd2[t][s] = cd2[t][bi]; cd2[t][bi] = tf;
                int ti = cidx[t][s]; cidx[t][s] = cidx[t][bi]; cidx[t][bi] = ti;
            }
            c = KMAX;
        }
        lcnt[t] = c;
    }
    __syncthreads();
    int off_q[5];
    off_q[0] = 0;
#pragma unroll
    for (int q = 0; q < 4; q++) off_q[q + 1] = off_q[q] + lcnt[q];
    const int total = off_q[4];           // <= 128
#pragma unroll
    for (int q = 0; q < 4; q++)
        if (t < lcnt[q]) eflat[off_q[q] + t] = (q << 14) | cidx[q][t];
    __syncthreads();

    // ---- cooperative per-edge feature build: thread e owns edge e
    if (t < total) {
        int pk = eflat[t];
        int j = pk & 0x3fff, q = pk >> 14;
        float4 qv = qp4[q];
        float rs = qv.w;
        float4 x4 = ((const float4*)xin)[j];
        float4 fa = make_float4(x4.x, x4.y, x4.z, x4.w);
        float4 fb;
        fb.x = (pos[3 * j + 0] - qv.x) * rs;
        fb.y = (pos[3 * j + 1] - qv.y) * rs;
        fb.z = (pos[3 * j + 2] - qv.z) * rs;
        fb.w = rfl[j] - rfl_i[q];
        ((float4*)feat[t])[0] = fa;
        ((float4*)feat[t])[1] = fb;
    }
    __syncthreads();

    // ---- phase 2a: all h1 -> LDS (f16), no global loads, no per-edge waits
    _Float16 (*h1all)[64] = (_Float16 (*)[64])shbuf;   // spos is dead
    for (int e = w; e < total; e += 4) {
        float4 fa = ((const float4*)feat[e])[0];       // broadcast b128
        float4 fb = ((const float4*)feat[e])[1];
        float a = b1c + fa.x * w1c[0] + fa.y * w1c[1] + fa.z * w1c[2] + fa.w * w1c[3]
                      + fb.x * w1c[4] + fb.y * w1c[5] + fb.z * w1c[6] + fb.w * w1c[7];
        float h1 = a > 0.f ? a : LK * a;
        h1all[e][lane] = (_Float16)h1;
    }
    __syncthreads();

    // ---- phase 2b: layer 2; consecutive edges independent -> pipelined LDS
    float vmax0 = -3.4e38f, vmax1 = -3.4e38f, vmax2 = -3.4e38f, vmax3 = -3.4e38f;
    float vmin0 = 3.4e38f, vmin1 = 3.4e38f, vmin2 = 3.4e38f, vmin3 = 3.4e38f;
    float ssum = 0.f, ssq = 0.f;
    for (int e = w; e < total; e += 4) {
        int qcur = eflat[e] >> 14;
        const float4* hp = (const float4*)h1all[e];
        float acc = b2c;
#pragma unroll
        for (int k = 0; k < 8; k++) {
            float4 rv = hp[k];                         // broadcast b128 = 8 halves
            half2v* h2p = (half2v*)&rv;
            acc = dot2f(h2p[0], w2c[4 * k + 0], acc);
            acc = dot2f(h2p[1], w2c[4 * k + 1], acc);
            acc = dot2f(h2p[2], w2c[4 * k + 2], acc);
            acc = dot2f(h2p[3], w2c[4 * k + 3], acc);
        }
        float h2 = acc > 0.f ? acc : LK * acc;
        if (qcur == 0)      { vmax0 = fmaxf(vmax0, h2); vmin0 = fminf(vmin0, h2); }
        else if (qcur == 1) { vmax1 = fmaxf(vmax1, h2); vmin1 = fminf(vmin1, h2); }
        else if (qcur == 2) { vmax2 = fmaxf(vmax2, h2); vmin2 = fminf(vmin2, h2); }
        else                { vmax3 = fmaxf(vmax3, h2); vmin3 = fminf(vmin3, h2); }
        ssum += h2; ssq += h2 * h2;
    }

    // ---- cross-wave max/min combine (reuse shbuf: [srcwave*4+q][64])
    float* cmbmax = (float*)shbuf;
    float* cmbmin = (float*)shbuf + 1024;
    __syncthreads();                       // h1all dead
    cmbmax[((w << 2) | 0) * 64 + lane] = vmax0;
    cmbmax[((w << 2) | 1) * 64 + lane] = vmax1;
    cmbmax[((w << 2) | 2) * 64 + lane] = vmax2;
    cmbmax[((w << 2) | 3) * 64 + lane] = vmax3;
    cmbmin[((w << 2) | 0) * 64 + lane] = vmin0;
    cmbmin[((w << 2) | 1) * 64 + lane] = vmin1;
    cmbmin[((w << 2) | 2) * 64 + lane] = vmin2;
    cmbmin[((w << 2) | 3) * 64 + lane] = vmin3;
    __syncthreads();
    {
        float mx = fmaxf(fmaxf(cmbmax[((0 << 2) | w) * 64 + lane], cmbmax[((1 << 2) | w) * 64 + lane]),
                         fmaxf(cmbmax[((2 << 2) | w) * 64 + lane], cmbmax[((3 << 2) | w) * 64 + lane]));
        float mn = fminf(fminf(cmbmin[((0 << 2) | w) * 64 + lane], cmbmin[((1 << 2) | w) * 64 + lane]),
                         fminf(cmbmin[((2 << 2) | w) * 64 + lane], cmbmin[((3 << 2) | w) * 64 + lane]));
        // sign(scl) = sign(gamma): select now, store one array
        vsel[(i0 + w) * 64 + lane] = (gamc >= 0.f) ? mx : mn;
    }
    // ---- BN stats: block-reduce then 16-way banked atomics
    red[t] = ssum;
    __syncthreads();
    if (t < 64) atomicAdd(&sums[((blockIdx.x & (NBANK - 1)) << 6) + t],
                          red[t] + red[t + 64] + red[t + 128] + red[t + 192]);
    __syncthreads();
    red[t] = ssq;
    __syncthreads();
    if (t < 64) atomicAdd(&sumsq[((blockIdx.x & (NBANK - 1)) << 6) + t],
                          red[t] + red[t + 64] + red[t + 128] + red[t + 192]);
    if (t == 0) atomicAdd(ecnt, total);
}

// ---------------- K2: BN affine + tuple passthrough, float4-vectorized
__global__ __launch_bounds__(256) void k2_fin(const float* __restrict__ wsf,
                                              const float* __restrict__ gamma,
                                              const float* __restrict__ beta,
                                              const float* __restrict__ pos,
                                              const int* __restrict__ braw,
                                              const float* __restrict__ rfl,
                                              const float* __restrict__ sf,
                                              float* __restrict__ out) {
    __shared__ float scl_s[64], shf_s[64];
    int tid = threadIdx.x;
    if (tid < 64) {
        float s = 0.f, s2 = 0.f;
#pragma unroll
        for (int b = 0; b < NBANK; b++) {
            s += wsf[F_SUMS + b * 64 + tid];
            s2 += wsf[F_SUMSQ + b * 64 + tid];
        }
        float cntf = (float)((const int*)wsf)[F_ECNT];
        float mean = s / cntf;
        float var = s2 / cntf - mean * mean;
        var = var > 0.f ? var : 0.f;
        float inv = 1.0f / sqrtf(var + EPSBN);
        float scl = gamma[tid] * inv;
        scl_s[tid] = scl;
        shf_s[tid] = beta[tid] - mean * scl;
    }
    __syncthreads();
    int o4 = blockIdx.x * 256 + tid;       // float4 index
    int o = o4 * 4;
    if (o >= O_TOT) return;
    float4 r;
    if (o < O_OUT) {
        float4 v = ((const float4*)(wsf + F_VSEL))[o4];
        int c = o & 63;
        r.x = scl_s[c + 0] * v.x + shf_s[c + 0];
        r.y = scl_s[c + 1] * v.y + shf_s[c + 1];
        r.z = scl_s[c + 2] * v.z + shf_s[c + 2];
        r.w = scl_s[c + 3] * v.w + shf_s[c + 3];
    } else if (o < O_POS) {
        r = ((const float4*)pos)[(o - O_OUT) >> 2];
    } else if (o < O_BAT) {
        int i = o - O_POS;
        int is64 = (braw[NP - 1] == 0) ? 1 : 0;
        r.x = (float)(is64 ? braw[2 * (i + 0)] : braw[i + 0]);
        r.y = (float)(is64 ? braw[2 * (i + 1)] : braw[i + 1]);
        r.z = (float)(is64 ? braw[2 * (i + 2)] : braw[i + 2]);
        r.w = (float)(is64 ? braw[2 * (i + 3)] : braw[i + 3]);
    } else if (o < O_RFL) {
        r = ((const float4*)rfl)[(o - O_BAT) >> 2];
    } else {
        r = ((const float4*)sf)[0];
    }
    ((float4*)out)[o4] = r;
}

extern "C" void kernel_launch(void* const* d_in, const int* in_sizes, int n_in,
                              void* d_out, int out_size, void* d_ws, size_t ws_size,
                              hipStream_t stream) {
    const float* xin  = (const float*)d_in[0];
    const float* pos  = (const float*)d_in[1];
    const float* rfl  = (const float*)d_in[2];
    const float* sf   = (const float*)d_in[3];
    const float* w1   = (const float*)d_in[4];
    const float* b1   = (const float*)d_in[5];
    const float* w2   = (const float*)d_in[6];
    const float* b2   = (const float*)d_in[7];
    const float* gam  = (const float*)d_in[8];
    const float* bet  = (const float*)d_in[9];
    const int*   brw  = (const int*)d_in[10];
    float* out = (float*)d_out;
    float* wsf = (float*)d_ws;

    hipMemsetAsync(d_ws, 0, (F_SUMSQ + 1024) * 4, stream);   // ecnt + sums + sumsq

    k1_fused<<<NP / 4, 256, 0, stream>>>(xin, pos, rfl, sf, w1, b1, w2, b2,
                                         gam, brw, wsf);
    int n4 = (O_TOT + 3) / 4;
    k2_fin<<<(n4 + 255) / 256, 256, 0, stream>>>(wsf, gam, bet, pos, brw, rfl, sf, out);
}